// Round 1
// baseline (203.230 us; speedup 1.0000x reference)
//
#include <hip/hip_runtime.h>

typedef unsigned short u16;
typedef unsigned int u32;
typedef __attribute__((ext_vector_type(8))) short short8;
typedef __attribute__((ext_vector_type(4))) float floatx4;

#define BN 8192
#define DIM 256
#define BM 64
#define BKN 64
#define NSPLIT 4
#define KPS (BN / NSPLIT)   // 2048 keys per split
#define NIT (KPS / BKN)     // 32 iterations
#define TSTRIDE 264         // key-major tile row stride (elems), pad 8: conflict-free b128
#define TTSTRIDE 72         // d-major tile row stride (elems), pad 8
#define PSTRIDE 72          // P row stride

__device__ __forceinline__ u16 f2bf(float x) {
    u32 u = __builtin_bit_cast(u32, x);
    u = (u + 0x7fffu + ((u >> 16) & 1u)) >> 16;
    return (u16)u;
}

// ---------------- kernel 1: row l2-normalize, write f as bf16 ----------------
__global__ __launch_bounds__(256) void k_norm(const float* __restrict__ in,
                                              u16* __restrict__ fb) {
    const int row = blockIdx.x * 4 + (threadIdx.x >> 6);
    const int lane = threadIdx.x & 63;
    const float4 v = *(const float4*)(in + (size_t)row * DIM + lane * 4);
    float ss = v.x * v.x + v.y * v.y + v.z * v.z + v.w * v.w;
    #pragma unroll
    for (int off = 1; off < 64; off <<= 1) ss += __shfl_xor(ss, off, 64);
    const float inv = 1.0f / fmaxf(sqrtf(ss), 1e-12f);
    u16 h0 = f2bf(v.x * inv), h1 = f2bf(v.y * inv), h2 = f2bf(v.z * inv), h3 = f2bf(v.w * inv);
    u16* p = fb + (size_t)row * DIM + lane * 4;
    p[0] = h0; p[1] = h1; p[2] = h2; p[3] = h3;
}

// ---------------- kernel 2: transpose f (bf16) -> fT [DIM][BN] ----------------
__global__ __launch_bounds__(1024) void k_transpose(const u16* __restrict__ fb,
                                                    u16* __restrict__ ft) {
    __shared__ u16 t[32][33];
    const int r0 = blockIdx.x * 32;   // row block in f
    const int c0 = blockIdx.y * 32;   // col block in f
    const int tx = threadIdx.x, ty = threadIdx.y;
    t[ty][tx] = fb[(size_t)(r0 + ty) * DIM + c0 + tx];
    __syncthreads();
    ft[(size_t)(c0 + ty) * BN + r0 + tx] = t[tx][ty];
}

// ---------------- kernel 3: flash attention (split-K) ----------------
// grid = (BN/BM)*NSPLIT blocks, 256 threads (4 waves, 16 Q-rows per wave)
__global__ __launch_bounds__(256, 2) void k_flash(
        const u16* __restrict__ fb, const u16* __restrict__ ft,
        float* __restrict__ Opart, float* __restrict__ mpart, float* __restrict__ lpart) {
    __shared__ u16 tile[BKN * TSTRIDE];    // [key][d]   33792 B
    __shared__ u16 tileT[DIM * TTSTRIDE];  // [d][key]   36864 B
    __shared__ u16 plds[4 * 16 * PSTRIDE]; // per-wave P [q][key]  9216 B

    const int tid = threadIdx.x;
    const int wave = tid >> 6, lane = tid & 63;
    const int c = lane & 15, g = lane >> 4;
    const int split = blockIdx.x & (NSPLIT - 1);
    const int qblk = blockIdx.x >> 2;
    const int q0 = qblk * BM + wave * 16;
    const int k0s = split * KPS;

    // Q fragments: A-layout, row q0+c, d = kc*32 + g*8 + j
    short8 qf[8];
    const u16* qbase = fb + (size_t)(q0 + c) * DIM + g * 8;
    #pragma unroll
    for (int kc = 0; kc < 8; ++kc) qf[kc] = *(const short8*)(qbase + kc * 32);

    floatx4 oacc[16];
    #pragma unroll
    for (int i = 0; i < 16; ++i) oacc[i] = (floatx4){0.f, 0.f, 0.f, 0.f};
    float m4[4] = {-INFINITY, -INFINITY, -INFINITY, -INFINITY};
    float l4[4] = {0.f, 0.f, 0.f, 0.f};

    u16* pw = plds + wave * 16 * PSTRIDE;

    for (int it = 0; it < NIT; ++it) {
        const int key0 = k0s + it * BKN;
        __syncthreads();
        // stage key-major tile: 2048 chunks of 8 elems
        #pragma unroll
        for (int i = 0; i < 8; ++i) {
            const int ch = tid + i * 256;
            const int r = ch >> 5, c8 = ch & 31;
            short8 v = *(const short8*)(fb + (size_t)(key0 + r) * DIM + c8 * 8);
            *(short8*)(tile + r * TSTRIDE + c8 * 8) = v;
        }
        // stage d-major tile from fT
        #pragma unroll
        for (int i = 0; i < 8; ++i) {
            const int ch = tid + i * 256;
            const int d = ch >> 3, k8 = ch & 7;
            short8 v = *(const short8*)(ft + (size_t)d * BN + key0 + k8 * 8);
            *(short8*)(tileT + d * TTSTRIDE + k8 * 8) = v;
        }
        __syncthreads();

        // S = Q K^T : 4 N-subtiles of 16 keys
        floatx4 s[4];
        #pragma unroll
        for (int nt = 0; nt < 4; ++nt) {
            floatx4 a = (floatx4){0.f, 0.f, 0.f, 0.f};
            #pragma unroll
            for (int kc = 0; kc < 8; ++kc) {
                short8 b = *(const short8*)(tile + (nt * 16 + c) * TSTRIDE + kc * 32 + g * 8);
                a = __builtin_amdgcn_mfma_f32_16x16x32_bf16(qf[kc], b, a, 0, 0, 0);
            }
            s[nt] = a;
        }

        // online softmax (rows q_local = 4g + r, cols across 16 lanes + 4 subtiles)
        float mnew[4], alpha[4];
        #pragma unroll
        for (int r = 0; r < 4; ++r) {
            float t = fmaxf(fmaxf(s[0][r], s[1][r]), fmaxf(s[2][r], s[3][r]));
            t = fmaxf(t, __shfl_xor(t, 1, 64));
            t = fmaxf(t, __shfl_xor(t, 2, 64));
            t = fmaxf(t, __shfl_xor(t, 4, 64));
            t = fmaxf(t, __shfl_xor(t, 8, 64));
            mnew[r] = fmaxf(m4[r], t);
            alpha[r] = __expf(m4[r] - mnew[r]);
            m4[r] = mnew[r];
        }
        #pragma unroll
        for (int nt = 0; nt < 4; ++nt) {
            #pragma unroll
            for (int r = 0; r < 4; ++r) {
                float p = __expf(s[nt][r] - mnew[r]);
                s[nt][r] = p;
                pw[(g * 4 + r) * PSTRIDE + nt * 16 + c] = f2bf(p);
            }
        }
        #pragma unroll
        for (int r = 0; r < 4; ++r) {
            float t = s[0][r] + s[1][r] + s[2][r] + s[3][r];
            t += __shfl_xor(t, 1, 64);
            t += __shfl_xor(t, 2, 64);
            t += __shfl_xor(t, 4, 64);
            t += __shfl_xor(t, 8, 64);
            l4[r] = l4[r] * alpha[r] + t;
        }
        // rescale O only when max moved (rare after warmup)
        const int need = (alpha[0] < 1.f) | (alpha[1] < 1.f) | (alpha[2] < 1.f) | (alpha[3] < 1.f);
        if (__any(need)) {
            #pragma unroll
            for (int dt = 0; dt < 16; ++dt) {
                oacc[dt][0] *= alpha[0]; oacc[dt][1] *= alpha[1];
                oacc[dt][2] *= alpha[2]; oacc[dt][3] *= alpha[3];
            }
        }
        // O += P V : P A-frags from per-wave LDS, V B-frags from d-major tile
        short8 pf[2];
        #pragma unroll
        for (int ks = 0; ks < 2; ++ks)
            pf[ks] = *(const short8*)(pw + c * PSTRIDE + ks * 32 + g * 8);
        #pragma unroll
        for (int dt = 0; dt < 16; ++dt) {
            #pragma unroll
            for (int ks = 0; ks < 2; ++ks) {
                short8 b = *(const short8*)(tileT + (dt * 16 + c) * TTSTRIDE + ks * 32 + g * 8);
                oacc[dt] = __builtin_amdgcn_mfma_f32_16x16x32_bf16(pf[ks], b, oacc[dt], 0, 0, 0);
            }
        }
    }

    // epilogue: store unnormalized partial O, plus m,l per row
    const size_t base = ((size_t)split * BN + q0) * DIM;
    #pragma unroll
    for (int dt = 0; dt < 16; ++dt)
        #pragma unroll
        for (int r = 0; r < 4; ++r)
            Opart[base + (size_t)(g * 4 + r) * DIM + dt * 16 + c] = oacc[dt][r];
    if (c == 0) {
        #pragma unroll
        for (int r = 0; r < 4; ++r) {
            mpart[(size_t)split * BN + q0 + g * 4 + r] = m4[r];
            lpart[(size_t)split * BN + q0 + g * 4 + r] = l4[r];
        }
    }
}

// ---------------- kernel 4: merge splits, blend, final l2-normalize ----------------
__global__ __launch_bounds__(256) void k_combine(
        const float* __restrict__ feats, const float* __restrict__ Opart,
        const float* __restrict__ mpart, const float* __restrict__ lpart,
        float* __restrict__ out) {
    const int row = blockIdx.x * 4 + (threadIdx.x >> 6);
    const int lane = threadIdx.x & 63;

    float m[NSPLIT], l[NSPLIT];
    float M = -INFINITY;
    #pragma unroll
    for (int s = 0; s < NSPLIT; ++s) {
        m[s] = mpart[(size_t)s * BN + row];
        l[s] = lpart[(size_t)s * BN + row];
        M = fmaxf(M, m[s]);
    }
    float L = 0.f, w[NSPLIT];
    #pragma unroll
    for (int s = 0; s < NSPLIT; ++s) { w[s] = __expf(m[s] - M); L += w[s] * l[s]; }

    float ax = 0.f, ay = 0.f, az = 0.f, aw = 0.f;
    #pragma unroll
    for (int s = 0; s < NSPLIT; ++s) {
        const float4 o = *(const float4*)(Opart + ((size_t)s * BN + row) * DIM + lane * 4);
        ax += w[s] * o.x; ay += w[s] * o.y; az += w[s] * o.z; aw += w[s] * o.w;
    }
    const float invL = 1.0f / L;

    // recompute f = normalized feats row
    const float4 v = *(const float4*)(feats + (size_t)row * DIM + lane * 4);
    float ss = v.x * v.x + v.y * v.y + v.z * v.z + v.w * v.w;
    #pragma unroll
    for (int off = 1; off < 64; off <<= 1) ss += __shfl_xor(ss, off, 64);
    const float invf = 1.0f / fmaxf(sqrtf(ss), 1e-12f);

    float yx = 0.8f * v.x * invf + 0.2f * ax * invL;
    float yy = 0.8f * v.y * invf + 0.2f * ay * invL;
    float yz = 0.8f * v.z * invf + 0.2f * az * invL;
    float yw = 0.8f * v.w * invf + 0.2f * aw * invL;

    float s2 = yx * yx + yy * yy + yz * yz + yw * yw;
    #pragma unroll
    for (int off = 1; off < 64; off <<= 1) s2 += __shfl_xor(s2, off, 64);
    const float invn = 1.0f / fmaxf(sqrtf(s2), 1e-12f);

    float4 o; o.x = yx * invn; o.y = yy * invn; o.z = yz * invn; o.w = yw * invn;
    *(float4*)(out + (size_t)row * DIM + lane * 4) = o;
}

// ---------------- launcher ----------------
extern "C" void kernel_launch(void* const* d_in, const int* in_sizes, int n_in,
                              void* d_out, int out_size, void* d_ws, size_t ws_size,
                              hipStream_t stream) {
    const float* feats = (const float*)d_in[0];
    float* out = (float*)d_out;
    char* ws = (char*)d_ws;

    // ws layout: fb (bf16, 4MB) | ft (bf16, 4MB) | Opart (32MB) | mpart (128KB) | lpart (128KB)
    u16* fb = (u16*)ws;
    u16* ft = (u16*)(ws + (size_t)BN * DIM * 2);
    float* Op = (float*)(ws + (size_t)BN * DIM * 4);
    float* mp = (float*)(ws + (size_t)BN * DIM * 4 + (size_t)NSPLIT * BN * DIM * 4);
    float* lp = mp + (size_t)NSPLIT * BN;

    k_norm<<<BN / 4, 256, 0, stream>>>(feats, fb);
    k_transpose<<<dim3(BN / 32, DIM / 32), dim3(32, 32), 0, stream>>>(fb, ft);
    k_flash<<<(BN / BM) * NSPLIT, 256, 0, stream>>>(fb, ft, Op, mp, lp);
    k_combine<<<BN / 4, 256, 0, stream>>>(feats, Op, mp, lp, out);
}

// Round 2
// 181.514 us; speedup vs baseline: 1.1196x; 1.1196x over previous
//
#include <hip/hip_runtime.h>

typedef unsigned short u16;
typedef unsigned int u32;
typedef __attribute__((ext_vector_type(8))) short short8;
typedef __attribute__((ext_vector_type(16))) float floatx16;

#define BN 8192
#define DIM 256
#define NSPLIT 8
#define KPS (BN / NSPLIT)     // 1024 keys per split
#define BKN 64                // keys per iter
#define NIT (KPS / BKN)       // 16 iters

__device__ __forceinline__ u16 f2bf(float x) {
    u32 u = __builtin_bit_cast(u32, x);
    u = (u + 0x7fffu + ((u >> 16) & 1u)) >> 16;
    return (u16)u;
}
__device__ __forceinline__ float bf2f(u16 h) {
    return __builtin_bit_cast(float, (u32)h << 16);
}
__device__ __forceinline__ void gl_lds16(const void* g, void* l) {
    __builtin_amdgcn_global_load_lds(
        (const __attribute__((address_space(1))) u32*)g,
        (__attribute__((address_space(3))) u32*)l, 16, 0, 0);
}

// ---------------- kernel 1: row l2-normalize, write f as bf16 ----------------
__global__ __launch_bounds__(256) void k_norm(const float* __restrict__ in,
                                              u16* __restrict__ fb) {
    const int row = blockIdx.x * 4 + (threadIdx.x >> 6);
    const int lane = threadIdx.x & 63;
    const float4 v = *(const float4*)(in + (size_t)row * DIM + lane * 4);
    float ss = v.x * v.x + v.y * v.y + v.z * v.z + v.w * v.w;
    #pragma unroll
    for (int off = 1; off < 64; off <<= 1) ss += __shfl_xor(ss, off, 64);
    const float inv = 1.0f / fmaxf(sqrtf(ss), 1e-12f);
    u16* p = fb + (size_t)row * DIM + lane * 4;
    p[0] = f2bf(v.x * inv); p[1] = f2bf(v.y * inv);
    p[2] = f2bf(v.z * inv); p[3] = f2bf(v.w * inv);
}

// ---------------- kernel 2: transpose f (bf16) -> fT [DIM][BN] ----------------
// 64x64 tiles, 256 threads, vectorized global I/O (short8 both sides)
__global__ __launch_bounds__(256) void k_transpose(const u16* __restrict__ fb,
                                                   u16* __restrict__ ft) {
    __shared__ u16 t[64][68];   // stride 68: 8B-aligned rows, spreads banks
    const int r0 = blockIdx.x * 64, c0 = blockIdx.y * 64;
    const int tid = threadIdx.x;
    const int tr = tid >> 3, tc = tid & 7;
    #pragma unroll
    for (int h = 0; h < 2; ++h) {
        const u16* src = fb + (size_t)(r0 + h * 32 + tr) * DIM + c0 + tc * 8;
        ushort4 a = *(const ushort4*)(src);
        ushort4 b = *(const ushort4*)(src + 4);
        *(ushort4*)(&t[h * 32 + tr][tc * 8]) = a;
        *(ushort4*)(&t[h * 32 + tr][tc * 8 + 4]) = b;
    }
    __syncthreads();
    #pragma unroll
    for (int h = 0; h < 2; ++h) {
        const int cc = h * 32 + tr;          // tile column = output row c0+cc
        u16 tmp[8];
        #pragma unroll
        for (int i = 0; i < 8; ++i) tmp[i] = t[tc * 8 + i][cc];
        *(short8*)(ft + (size_t)(c0 + cc) * BN + r0 + tc * 8) = *(short8*)tmp;
    }
}

// ---------------- kernel 3: flash attention, no-max softmax, split-K ----------------
// grid = (BN/128)*NSPLIT = 512 blocks, 4 waves, 32 q-rows/wave, 32x32x16 MFMA
__global__ __launch_bounds__(256, 2) void k_flash(
        const u16* __restrict__ fb, const u16* __restrict__ ft,
        u16* __restrict__ Opart, float* __restrict__ lpart) {
    __shared__ u16 tileK[64 * 256];   // swizzled key-major K-tile, 32 KB
    __shared__ u16 tileV[256 * 64];   // swizzled d-major V-tile, 32 KB
    // P buffer aliases tileK (valid: all QK reads of tileK complete before P write)

    const int tid = threadIdx.x;
    const int wave = tid >> 6, lane = tid & 63;
    const int c31 = lane & 31, g1 = lane >> 5;
    const int sw7 = c31 & 7;
    const int split = blockIdx.x & (NSPLIT - 1);
    const int qblk = blockIdx.x >> 3;
    const int q0 = qblk * 128 + wave * 32;
    const int key0 = split * KPS;

    // Q B-frags (loop-invariant, regs): B[k=g1*8+j][n=c31] = Q[q0+c31][kc*16+g1*8+j]
    short8 qf[16];
    const u16* qb = fb + (size_t)(q0 + c31) * DIM + g1 * 8;
    #pragma unroll
    for (int kc = 0; kc < 16; ++kc) qf[kc] = *(const short8*)(qb + kc * 16);

    floatx16 oacc[8];
    #pragma unroll
    for (int i = 0; i < 8; ++i)
        #pragma unroll
        for (int r = 0; r < 16; ++r) oacc[i][r] = 0.f;
    float lp = 0.f;

    char* pw = (char*)tileK + wave * 4096;   // per-wave P: 32 q x 64 k bf16, swizzled

    for (int it = 0; it < NIT; ++it) {
        const int k0 = key0 + it * BKN;
        __syncthreads();   // everyone done with prev tiles + P
        // ---- DMA stage: wave w covers its 8KB quarter of each tile ----
        {
            const char* gK = (const char*)fb + (size_t)k0 * 512;
            char* lK = (char*)tileK + wave * 8192;
            #pragma unroll
            for (int i = 0; i < 8; ++i) {
                const int o = wave * 8192 + i * 1024 + lane * 16;
                const int r = o >> 9;
                const int ch = (o >> 4) & 31;
                const int c8 = (ch & ~7) | ((ch ^ r) & 7);   // swizzle on global side
                gl_lds16(gK + (size_t)r * 512 + c8 * 16, lK + i * 1024);
            }
            const char* gV = (const char*)ft + (size_t)k0 * 2;
            char* lV = (char*)tileV + wave * 8192;
            #pragma unroll
            for (int i = 0; i < 8; ++i) {
                const int o = wave * 8192 + i * 1024 + lane * 16;
                const int d = o >> 7;
                const int ch = (o >> 4) & 7;
                const int c8 = ch ^ (d & 7);
                gl_lds16(gV + (size_t)d * (BN * 2) + c8 * 16, lV + i * 1024);
            }
        }
        __syncthreads();   // vmcnt(0) drain: tiles ready

        // ---- S^T = K * Q^T : rows=keys, cols=q (C/D: col=lane&31=q) ----
        floatx16 s0, s1;
        #pragma unroll
        for (int r = 0; r < 16; ++r) { s0[r] = 0.f; s1[r] = 0.f; }
        #pragma unroll
        for (int kc = 0; kc < 16; ++kc) {
            const int ch = kc * 2 + g1;
            const int sw = (ch & ~7) | ((ch ^ c31) & 7);
            short8 a0 = *(const short8*)((const char*)tileK + c31 * 512 + sw * 16);
            short8 a1 = *(const short8*)((const char*)tileK + (32 + c31) * 512 + sw * 16);
            s0 = __builtin_amdgcn_mfma_f32_32x32x16_bf16(a0, qf[kc], s0, 0, 0, 0);
            s1 = __builtin_amdgcn_mfma_f32_32x32x16_bf16(a1, qf[kc], s1, 0, 0, 0);
        }
        __syncthreads();   // all QK reads of tileK done -> safe to write P into alias

        // ---- P = exp(S) (no max: cosine sims <= ~1), packed b64 stores ----
        #pragma unroll
        for (int nt = 0; nt < 2; ++nt) {
            const floatx16 sv = nt ? s1 : s0;
            #pragma unroll
            for (int rr = 0; rr < 4; ++rr) {
                const float e0 = __expf(sv[4 * rr + 0]);
                const float e1 = __expf(sv[4 * rr + 1]);
                const float e2 = __expf(sv[4 * rr + 2]);
                const float e3 = __expf(sv[4 * rr + 3]);
                lp += (e0 + e1) + (e2 + e3);
                ushort4 pk;
                pk.x = f2bf(e0); pk.y = f2bf(e1); pk.z = f2bf(e2); pk.w = f2bf(e3);
                // keys nt*32 + 8*rr + 4*g1 + 0..3 ; chunk = nt*4+rr, swizzle ^ (q&7)
                const int sz = (nt * 4 + rr) ^ sw7;
                *(ushort4*)(pw + c31 * 128 + sz * 16 + g1 * 8) = pk;
            }
        }

        // ---- O += P * V : A=P (own-wave LDS), B=V from tileV ----
        #pragma unroll
        for (int ks = 0; ks < 4; ++ks) {
            const int sz = (ks * 2 + g1) ^ sw7;
            short8 pf = *(const short8*)(pw + c31 * 128 + sz * 16);
            #pragma unroll
            for (int ds = 0; ds < 8; ++ds) {
                // d = ds*32+c31, d&7 == c31&7 -> same swizzle
                short8 vf = *(const short8*)((const char*)tileV + (ds * 32 + c31) * 128 + sz * 16);
                oacc[ds] = __builtin_amdgcn_mfma_f32_32x32x16_bf16(pf, vf, oacc[ds], 0, 0, 0);
            }
        }
    }

    // ---- epilogue: bf16 partial O + fp32 partial l ----
    u16* ob = Opart + ((size_t)split * BN + q0) * DIM;
    #pragma unroll
    for (int ds = 0; ds < 8; ++ds) {
        #pragma unroll
        for (int r = 0; r < 16; ++r) {
            const int ql = (r & 3) + 8 * (r >> 2) + 4 * g1;
            ob[(size_t)ql * DIM + ds * 32 + c31] = f2bf(oacc[ds][r]);
        }
    }
    lp += __shfl_xor(lp, 32, 64);
    if (g1 == 0) lpart[(size_t)split * BN + q0 + c31] = lp;
}

// ---------------- kernel 4: merge splits, blend, final l2-normalize ----------------
__global__ __launch_bounds__(256) void k_combine(
        const float* __restrict__ feats, const u16* __restrict__ Opart,
        const float* __restrict__ lpart, float* __restrict__ out) {
    const int row = blockIdx.x * 4 + (threadIdx.x >> 6);
    const int lane = threadIdx.x & 63;

    float L = 0.f;
    #pragma unroll
    for (int s = 0; s < NSPLIT; ++s) L += lpart[(size_t)s * BN + row];

    float a0 = 0.f, a1 = 0.f, a2 = 0.f, a3 = 0.f;
    #pragma unroll
    for (int s = 0; s < NSPLIT; ++s) {
        const ushort4 o = *(const ushort4*)(Opart + ((size_t)s * BN + row) * DIM + lane * 4);
        a0 += bf2f(o.x); a1 += bf2f(o.y); a2 += bf2f(o.z); a3 += bf2f(o.w);
    }
    const float invL = 1.0f / L;

    const float4 v = *(const float4*)(feats + (size_t)row * DIM + lane * 4);
    float ss = v.x * v.x + v.y * v.y + v.z * v.z + v.w * v.w;
    #pragma unroll
    for (int off = 1; off < 64; off <<= 1) ss += __shfl_xor(ss, off, 64);
    const float invf = 1.0f / fmaxf(sqrtf(ss), 1e-12f);

    const float yx = 0.8f * v.x * invf + 0.2f * a0 * invL;
    const float yy = 0.8f * v.y * invf + 0.2f * a1 * invL;
    const float yz = 0.8f * v.z * invf + 0.2f * a2 * invL;
    const float yw = 0.8f * v.w * invf + 0.2f * a3 * invL;

    float s2 = yx * yx + yy * yy + yz * yz + yw * yw;
    #pragma unroll
    for (int off = 1; off < 64; off <<= 1) s2 += __shfl_xor(s2, off, 64);
    const float invn = 1.0f / fmaxf(sqrtf(s2), 1e-12f);

    float4 o; o.x = yx * invn; o.y = yy * invn; o.z = yz * invn; o.w = yw * invn;
    *(float4*)(out + (size_t)row * DIM + lane * 4) = o;
}

// ---------------- launcher ----------------
extern "C" void kernel_launch(void* const* d_in, const int* in_sizes, int n_in,
                              void* d_out, int out_size, void* d_ws, size_t ws_size,
                              hipStream_t stream) {
    const float* feats = (const float*)d_in[0];
    float* out = (float*)d_out;
    char* ws = (char*)d_ws;

    // ws: fb bf16 4MB | ft bf16 4MB | Opart bf16 32MB | lpart fp32 256KB  (~40.3MB)
    u16* fb = (u16*)ws;
    u16* ft = (u16*)(ws + (size_t)BN * DIM * 2);
    u16* Op = (u16*)(ws + (size_t)BN * DIM * 4);
    float* lp = (float*)(ws + (size_t)BN * DIM * 4 + (size_t)NSPLIT * BN * DIM * 2);

    k_norm<<<BN / 4, 256, 0, stream>>>(feats, fb);
    k_transpose<<<dim3(BN / 64, DIM / 64), 256, 0, stream>>>(fb, ft);
    k_flash<<<(BN / 128) * NSPLIT, 256, 0, stream>>>(fb, ft, Op, lp);
    k_combine<<<BN / 4, 256, 0, stream>>>(feats, Op, lp, out);
}

// Round 3
// 169.536 us; speedup vs baseline: 1.1987x; 1.0707x over previous
//
#include <hip/hip_runtime.h>

typedef unsigned short u16;
typedef unsigned int u32;
typedef unsigned long long u64;
typedef __attribute__((ext_vector_type(8))) short short8;
typedef __attribute__((ext_vector_type(16))) float floatx16;

#define BN 8192
#define DIM 256
#define NSPLIT 8
#define KPS (BN / NSPLIT)     // 1024 keys per split
#define BKN 32                // keys per iter
#define NIT (KPS / BKN)       // 32 iters

__device__ __forceinline__ u16 f2bf(float x) {
    u32 u = __builtin_bit_cast(u32, x);
    u = (u + 0x7fffu + ((u >> 16) & 1u)) >> 16;
    return (u16)u;
}
__device__ __forceinline__ float bf2f(u16 h) {
    return __builtin_bit_cast(float, (u32)h << 16);
}
__device__ __forceinline__ u64 pack4(float a, float b, float c, float d) {
    return (u64)f2bf(a) | ((u64)f2bf(b) << 16) | ((u64)f2bf(c) << 32) | ((u64)f2bf(d) << 48);
}
__device__ __forceinline__ void gl_lds16(const void* g, void* l) {
    __builtin_amdgcn_global_load_lds(
        (const __attribute__((address_space(1))) u32*)g,
        (__attribute__((address_space(3))) u32*)l, 16, 0, 0);
}

// ---------------- kernel 1: fused row l2-norm (fp32->bf16) + transpose ----------------
// 128 blocks x 256 thr; block handles 64 rows; writes fb row-major and ft d-major.
__global__ __launch_bounds__(256) void k_prep(const float* __restrict__ in,
                                              u16* __restrict__ fb, u16* __restrict__ ft) {
    __shared__ u16 t[64 * 260];
    const int tid = threadIdx.x;
    const int wave = tid >> 6, lane = tid & 63;
    const int r0 = blockIdx.x * 64;
    #pragma unroll 4
    for (int i = 0; i < 16; ++i) {
        const int rl = wave * 16 + i;
        const float4 v = *(const float4*)(in + (size_t)(r0 + rl) * DIM + lane * 4);
        float ss = v.x * v.x + v.y * v.y + v.z * v.z + v.w * v.w;
        #pragma unroll
        for (int off = 1; off < 64; off <<= 1) ss += __shfl_xor(ss, off, 64);
        const float inv = 1.0f / fmaxf(sqrtf(ss), 1e-12f);
        const u64 p = pack4(v.x * inv, v.y * inv, v.z * inv, v.w * inv);
        *(u64*)(fb + (size_t)(r0 + rl) * DIM + lane * 4) = p;
        *(u64*)(&t[rl * 260 + lane * 4]) = p;
    }
    __syncthreads();
    const int rg = tid & 7, dg = tid >> 3;   // 8 row-groups x 32 d-groups
    #pragma unroll
    for (int i = 0; i < 8; ++i) {
        const int d = dg * 8 + i;
        short8 w;
        #pragma unroll
        for (int j = 0; j < 8; ++j) w[j] = (short)t[(rg * 8 + j) * 260 + d];
        *(short8*)(ft + (size_t)d * BN + r0 + rg * 8) = w;
    }
}

// ---------------- kernel 2: flash attention, no-max softmax, split-K ----------------
// grid = (BN/128)*NSPLIT = 512 blocks, 4 waves, 32 q/wave, 32x32x16 MFMA.
// Double-buffered tiles, ONE barrier per iter; DMA(it+1) issued after the barrier
// and drained only at the next barrier (one full compute phase of latency hiding).
__global__ __launch_bounds__(256, 2) void k_flash(
        const u16* __restrict__ fb, const u16* __restrict__ ft,
        u16* __restrict__ Opart, float* __restrict__ lpart) {
    __shared__ u16 tileK[2][32 * 256];   // key-major, chunk-swizzled; 16 KB each
    __shared__ u16 tileV[2][32 * 256];   // d-major, row-pair-interleaved slots; 16 KB each
    __shared__ u16 plds[4][1024];        // per-wave P, 32q x 32k, slot layout; 2 KB each

    const int tid = threadIdx.x;
    const int wave = tid >> 6, lane = tid & 63;
    const int c31 = lane & 31, g1 = lane >> 5;
    const int split = blockIdx.x & (NSPLIT - 1);
    const int qblk = blockIdx.x >> 3;
    const int q0 = qblk * 128 + wave * 32;
    const int key0 = split * KPS;

    // Q B-frags (loop-invariant): B[k=g1*8+j][n=c31] = Q[q0+c31][kc*16+g1*8+j]
    short8 qf[16];
    const u16* qb = fb + (size_t)(q0 + c31) * DIM + g1 * 8;
    #pragma unroll
    for (int kc = 0; kc < 16; ++kc) qf[kc] = *(const short8*)(qb + kc * 16);

    floatx16 oacc[8];
    #pragma unroll
    for (int i = 0; i < 8; ++i)
        #pragma unroll
        for (int r = 0; r < 16; ++r) oacc[i][r] = 0.f;
    float lp = 0.f;

    // Loop-invariant DMA lane offsets (global-side swizzle; LDS dst is contiguous).
    int offK[4], offV[4];
    #pragma unroll
    for (int i = 0; i < 4; ++i) {
        const int L = wave * 256 + i * 64 + lane;
        {   // K: slot L holds (r = L>>5, c = (cs&~7)|((cs^r)&7))
            const int r = L >> 5, cs = L & 31;
            const int c = (cs & ~7) | ((cs ^ r) & 7);
            offK[i] = r * 512 + c * 16;
        }
        {   // V: slot L holds (d = 2*(L>>3)+(L&1), c = ((L>>1)&3 - line)&3)
            const int line = L >> 3, w8 = L & 7;
            const int d = line * 2 + (w8 & 1);
            const int c = ((w8 >> 1) - line) & 3;
            offV[i] = d * (BN * 2) + c * 16;
        }
    }
    const char* gK = (const char*)fb + (size_t)key0 * 512;
    const char* gV = (const char*)ft + (size_t)key0 * 2;
    u16* const pb = &plds[wave][0];
    const int swp = (c31 >> 1) & 3;      // P/V line swizzle component for this lane's q
    const int parq = c31 & 1;

    // stage iteration `s` into buffer b
    auto stage = [&](int s, int b) {
        const size_t kOff = (size_t)s * (BKN * 512);
        const size_t vOff = (size_t)s * (BKN * 2);
        char* lK = (char*)&tileK[b][0] + wave * 4096;
        char* lV = (char*)&tileV[b][0] + wave * 4096;
        #pragma unroll
        for (int i = 0; i < 4; ++i) gl_lds16(gK + kOff + offK[i], lK + i * 1024);
        #pragma unroll
        for (int i = 0; i < 4; ++i) gl_lds16(gV + vOff + offV[i], lV + i * 1024);
    };

    stage(0, 0);
    for (int it = 0; it < NIT; ++it) {
        const int b = it & 1;
        __syncthreads();                       // drains DMA(it) (issued one iter ago)
        if (it + 1 < NIT) stage(it + 1, b ^ 1);

        // ---- S^T = K * Q^T (contract d=256, 16 MFMA) ----
        floatx16 s;
        #pragma unroll
        for (int r = 0; r < 16; ++r) s[r] = 0.f;
        const char* tk = (const char*)&tileK[b][0];
        #pragma unroll
        for (int kc = 0; kc < 16; ++kc) {
            const int ch = kc * 2 + g1;
            const int sw = (ch & ~7) | ((ch ^ c31) & 7);
            const short8 a = *(const short8*)(tk + c31 * 512 + sw * 16);
            s = __builtin_amdgcn_mfma_f32_32x32x16_bf16(a, qf[kc], s, 0, 0, 0);
        }

        // ---- P = exp(S), pack to 16B chunks via half-wave exchange ----
        float e[16];
        #pragma unroll
        for (int r = 0; r < 16; ++r) { e[r] = __expf(s[r]); lp += e[r]; }
        const u64 u0 = pack4(e[0], e[1], e[2], e[3]);      // granule 0+g1
        const u64 u1 = pack4(e[4], e[5], e[6], e[7]);      // granule 2+g1
        const u64 u2 = pack4(e[8], e[9], e[10], e[11]);    // granule 4+g1
        const u64 u3 = pack4(e[12], e[13], e[14], e[15]);  // granule 6+g1
        const u64 r0x = (u64)__shfl_xor((long long)(g1 ? u0 : u2), 32, 64);
        const u64 r1x = (u64)__shfl_xor((long long)(g1 ? u1 : u3), 32, 64);
        u64 loA = g1 ? r0x : u0, hiA = g1 ? u2 : r0x;      // chunk 2*g1
        u64 loB = g1 ? r1x : u1, hiB = g1 ? u3 : r1x;      // chunk 2*g1+1
        {
            const int cwA = 2 * g1, cwB = 2 * g1 + 1;
            const int spA = (c31 >> 1) * 8 + 2 * ((cwA + swp) & 3) + parq;
            const int spB = (c31 >> 1) * 8 + 2 * ((cwB + swp) & 3) + parq;
            u64* dA = (u64*)((char*)pb + spA * 16);
            u64* dB = (u64*)((char*)pb + spB * 16);
            dA[0] = loA; dA[1] = hiA;
            dB[0] = loB; dB[1] = hiB;
        }

        // ---- O += P * V (contract 32 keys, 16 MFMA) ----
        const char* tv = (const char*)&tileV[b][0];
        #pragma unroll
        for (int kc2 = 0; kc2 < 2; ++kc2) {
            const int c = kc2 * 2 + g1;
            const int sp = (c31 >> 1) * 8 + 2 * ((c + swp) & 3) + parq;
            const short8 pf = *(const short8*)((const char*)pb + sp * 16);
            #pragma unroll
            for (int ds = 0; ds < 8; ++ds) {
                const int sv = (16 * ds + (c31 >> 1)) * 8 + 2 * ((c + swp) & 3) + parq;
                const short8 vf = *(const short8*)(tv + sv * 16);
                oacc[ds] = __builtin_amdgcn_mfma_f32_32x32x16_bf16(pf, vf, oacc[ds], 0, 0, 0);
            }
        }
    }

    // ---- epilogue: bf16 partial O + fp32 partial l ----
    u16* ob = Opart + ((size_t)split * BN + q0) * DIM;
    #pragma unroll
    for (int ds = 0; ds < 8; ++ds) {
        #pragma unroll
        for (int r = 0; r < 16; ++r) {
            const int ql = (r & 3) + 8 * (r >> 2) + 4 * g1;
            ob[(size_t)ql * DIM + ds * 32 + c31] = f2bf(oacc[ds][r]);
        }
    }
    lp += __shfl_xor(lp, 32, 64);
    if (g1 == 0) lpart[(size_t)split * BN + q0 + c31] = lp;
}

// ---------------- kernel 3: merge splits, blend, final l2-normalize ----------------
__global__ __launch_bounds__(256) void k_combine(
        const float* __restrict__ feats, const u16* __restrict__ Opart,
        const float* __restrict__ lpart, float* __restrict__ out) {
    const int row = blockIdx.x * 4 + (threadIdx.x >> 6);
    const int lane = threadIdx.x & 63;

    float L = 0.f;
    #pragma unroll
    for (int s = 0; s < NSPLIT; ++s) L += lpart[(size_t)s * BN + row];

    float a0 = 0.f, a1 = 0.f, a2 = 0.f, a3 = 0.f;
    #pragma unroll
    for (int s = 0; s < NSPLIT; ++s) {
        const ushort4 o = *(const ushort4*)(Opart + ((size_t)s * BN + row) * DIM + lane * 4);
        a0 += bf2f(o.x); a1 += bf2f(o.y); a2 += bf2f(o.z); a3 += bf2f(o.w);
    }
    const float invL = 1.0f / L;

    const float4 v = *(const float4*)(feats + (size_t)row * DIM + lane * 4);
    float ss = v.x * v.x + v.y * v.y + v.z * v.z + v.w * v.w;
    #pragma unroll
    for (int off = 1; off < 64; off <<= 1) ss += __shfl_xor(ss, off, 64);
    const float invf = 1.0f / fmaxf(sqrtf(ss), 1e-12f);

    const float yx = 0.8f * v.x * invf + 0.2f * a0 * invL;
    const float yy = 0.8f * v.y * invf + 0.2f * a1 * invL;
    const float yz = 0.8f * v.z * invf + 0.2f * a2 * invL;
    const float yw = 0.8f * v.w * invf + 0.2f * a3 * invL;

    float s2 = yx * yx + yy * yy + yz * yz + yw * yw;
    #pragma unroll
    for (int off = 1; off < 64; off <<= 1) s2 += __shfl_xor(s2, off, 64);
    const float invn = 1.0f / fmaxf(sqrtf(s2), 1e-12f);

    float4 o; o.x = yx * invn; o.y = yy * invn; o.z = yz * invn; o.w = yw * invn;
    *(float4*)(out + (size_t)row * DIM + lane * 4) = o;
}

// ---------------- launcher ----------------
extern "C" void kernel_launch(void* const* d_in, const int* in_sizes, int n_in,
                              void* d_out, int out_size, void* d_ws, size_t ws_size,
                              hipStream_t stream) {
    const float* feats = (const float*)d_in[0];
    float* out = (float*)d_out;
    char* ws = (char*)d_ws;

    // ws: fb bf16 4MB | ft bf16 4MB | Opart bf16 32MB | lpart fp32 256KB
    u16* fb = (u16*)ws;
    u16* ft = (u16*)(ws + (size_t)BN * DIM * 2);
    u16* Op = (u16*)(ws + (size_t)BN * DIM * 4);
    float* lp = (float*)(ws + (size_t)BN * DIM * 4 + (size_t)NSPLIT * BN * DIM * 2);

    k_prep<<<BN / 64, 256, 0, stream>>>(feats, fb, ft);
    k_flash<<<(BN / 128) * NSPLIT, 256, 0, stream>>>(fb, ft, Op, lp);
    k_combine<<<BN / 4, 256, 0, stream>>>(feats, Op, lp, out);
}

// Round 4
// 149.928 us; speedup vs baseline: 1.3555x; 1.1308x over previous
//
#include <hip/hip_runtime.h>

typedef unsigned short u16;
typedef unsigned int u32;
typedef unsigned long long u64;
typedef __attribute__((ext_vector_type(8))) short short8;
typedef __attribute__((ext_vector_type(16))) float floatx16;

#define BN 8192
#define DIM 256
#define NSPLIT 8
#define KPS (BN / NSPLIT)     // 1024 keys per split
#define BKN 32                // keys per iter
#define NIT (KPS / BKN)       // 32 iters

__device__ __forceinline__ u16 f2bf(float x) {
    u32 u = __builtin_bit_cast(u32, x);
    u = (u + 0x7fffu + ((u >> 16) & 1u)) >> 16;
    return (u16)u;
}
__device__ __forceinline__ float bf2f(u16 h) {
    return __builtin_bit_cast(float, (u32)h << 16);
}
__device__ __forceinline__ u64 pack4(float a, float b, float c, float d) {
    return (u64)f2bf(a) | ((u64)f2bf(b) << 16) | ((u64)f2bf(c) << 32) | ((u64)f2bf(d) << 48);
}
__device__ __forceinline__ short8 mk8(u64 lo, u64 hi) {
    struct P16 { u64 a, b; } p{lo, hi};
    return __builtin_bit_cast(short8, p);
}
__device__ __forceinline__ void gl_lds16(const void* g, void* l) {
    __builtin_amdgcn_global_load_lds(
        (const __attribute__((address_space(1))) u32*)g,
        (__attribute__((address_space(3))) u32*)l, 16, 0, 0);
}

// ---------------- kernel 1: row l2-norm + pre-tiled/pre-swizzled V images ----------------
// 256 blocks x 256 thr; block kb handles keys kb*32..kb*32+31.
// fv[kb] is the EXACT 16 KB LDS image the flash kernel wants:
//   slot(l,c,p) = l*8 + 2*((c + (l&3))&3) + p  holds V[8c+j][2l+p], j=0..7 (16 B)
__global__ __launch_bounds__(256) void k_prep(const float* __restrict__ in,
                                              u16* __restrict__ fb, u16* __restrict__ fv) {
    __shared__ u16 t[32 * 260];
    const int tid = threadIdx.x;
    const int wave = tid >> 6, lane = tid & 63;
    const int kb = blockIdx.x, r0 = kb * 32;
    #pragma unroll
    for (int i = 0; i < 8; ++i) {
        const int rl = wave * 8 + i;
        const float4 v = *(const float4*)(in + (size_t)(r0 + rl) * DIM + lane * 4);
        float ss = v.x * v.x + v.y * v.y + v.z * v.z + v.w * v.w;
        #pragma unroll
        for (int off = 1; off < 64; off <<= 1) ss += __shfl_xor(ss, off, 64);
        const float inv = 1.0f / fmaxf(sqrtf(ss), 1e-12f);
        const u64 p = pack4(v.x * inv, v.y * inv, v.z * inv, v.w * inv);
        *(u64*)(fb + (size_t)(r0 + rl) * DIM + lane * 4) = p;
        *(u64*)(&t[rl * 260 + lane * 4]) = p;
    }
    __syncthreads();
    #pragma unroll
    for (int i = 0; i < 4; ++i) {
        const int S = tid + 256 * i;          // slot index 0..1023
        const int l = S >> 3, w = S & 7;
        const int p = w & 1;
        const int c = ((w >> 1) - l) & 3;
        u16 tmp[8];
        #pragma unroll
        for (int j = 0; j < 8; ++j) tmp[j] = t[(8 * c + j) * 260 + 2 * l + p];
        *(short8*)(fv + (size_t)kb * 8192 + S * 8) = *(short8*)tmp;
    }
}

// ---------------- kernel 2: flash attention, no-max softmax, split-K ----------------
// 512 blocks, 4 waves, 32 q/wave, 32x32x16 MFMA. Double-buffered tiles, 1 barrier/iter.
// P stays in registers: S^T C/D layout (col=q) == PV A layout (m=q); one shfl_xor(32)
// of packed u64 granules builds the A-frags. V DMA is a linear copy of fv's tile image.
__global__ __launch_bounds__(256, 2) void k_flash(
        const u16* __restrict__ fb, const u16* __restrict__ fv,
        u16* __restrict__ Opart, float* __restrict__ lpart) {
    __shared__ u16 tileK[2][32 * 256];   // key-major, chunk-swizzled, 16 KB each
    __shared__ u16 tileV[2][32 * 256];   // pre-swizzled V image, 16 KB each

    const int tid = threadIdx.x;
    const int wave = tid >> 6, lane = tid & 63;
    const int c31 = lane & 31, g1 = lane >> 5;
    const int split = blockIdx.x & (NSPLIT - 1);
    const int qblk = blockIdx.x >> 3;
    const int q0 = qblk * 128 + wave * 32;
    const int key0 = split * KPS;

    // Q B-frags (loop-invariant): B[k=g1*8+j][n=c31] = Q[q0+c31][kc*16+g1*8+j]
    short8 qf[16];
    const u16* qb = fb + (size_t)(q0 + c31) * DIM + g1 * 8;
    #pragma unroll
    for (int kc = 0; kc < 16; ++kc) qf[kc] = *(const short8*)(qb + kc * 16);

    floatx16 oacc[8];
    #pragma unroll
    for (int i = 0; i < 8; ++i)
        #pragma unroll
        for (int r = 0; r < 16; ++r) oacc[i][r] = 0.f;
    float lp = 0.f;

    // K DMA source offsets (swizzle on global side; 1 KB contiguous per instr)
    int offK[4];
    #pragma unroll
    for (int i = 0; i < 4; ++i) {
        const int L = wave * 256 + i * 64 + lane;
        const int r = L >> 5, cs = L & 31;
        const int c = (cs & ~7) | ((cs ^ r) & 7);
        offK[i] = r * 512 + c * 16;
    }
    const char* gK = (const char*)fb + (size_t)key0 * 512;
    const char* gV = (const char*)fv + (size_t)(key0 >> 5) * 16384;
    const int swp = (c31 >> 1) & 3;
    const int parq = c31 & 1;

    auto stage = [&](int s, int b) {
        const size_t o = (size_t)s * 16384;
        char* lK = (char*)&tileK[b][0] + wave * 4096;
        char* lV = (char*)&tileV[b][0] + wave * 4096;
        #pragma unroll
        for (int i = 0; i < 4; ++i) gl_lds16(gK + o + offK[i], lK + i * 1024);
        #pragma unroll
        for (int i = 0; i < 4; ++i)
            gl_lds16(gV + o + wave * 4096 + i * 1024 + lane * 16, lV + i * 1024);
    };

    stage(0, 0);
    for (int it = 0; it < NIT; ++it) {
        const int b = it & 1;
        __syncthreads();                       // drains DMA(it), issued one iter ago
        if (it + 1 < NIT) stage(it + 1, b ^ 1);

        // ---- S^T = K * Q^T (contract d=256, 16 MFMA) ----
        floatx16 s;
        #pragma unroll
        for (int r = 0; r < 16; ++r) s[r] = 0.f;
        const char* tk = (const char*)&tileK[b][0];
        #pragma unroll
        for (int kc = 0; kc < 16; ++kc) {
            const int ch = kc * 2 + g1;
            const int sw = (ch & ~7) | ((ch ^ c31) & 7);
            const short8 a = *(const short8*)(tk + c31 * 512 + sw * 16);
            s = __builtin_amdgcn_mfma_f32_32x32x16_bf16(a, qf[kc], s, 0, 0, 0);
        }

        // ---- P = exp(S) in registers; build A-frags via half-wave exchange ----
        float e[16];
        #pragma unroll
        for (int r = 0; r < 16; ++r) { e[r] = __expf(s[r]); lp += e[r]; }
        // u_rr holds keys 8*rr + 4*g1 + 0..3 (row q=c31)
        const u64 u0 = pack4(e[0], e[1], e[2], e[3]);
        const u64 u1 = pack4(e[4], e[5], e[6], e[7]);
        const u64 u2 = pack4(e[8], e[9], e[10], e[11]);
        const u64 u3 = pack4(e[12], e[13], e[14], e[15]);
        const u64 x0 = (u64)__shfl_xor((long long)(g1 ? u0 : u1), 32, 64);
        const u64 x1 = (u64)__shfl_xor((long long)(g1 ? u2 : u3), 32, 64);
        const short8 A0 = g1 ? mk8(x0, u1) : mk8(u0, x0);   // keys kc2=0: 0..15
        const short8 A1 = g1 ? mk8(x1, u3) : mk8(u2, x1);   // keys kc2=1: 16..31

        // ---- O += P * V (contract 32 keys, 16 MFMA) ----
        const char* tv = (const char*)&tileV[b][0];
        #pragma unroll
        for (int kc2 = 0; kc2 < 2; ++kc2) {
            const short8 pf = kc2 ? A1 : A0;
            const int cc = kc2 * 2 + g1;
            #pragma unroll
            for (int ds = 0; ds < 8; ++ds) {
                const int sv = (16 * ds + (c31 >> 1)) * 8 + 2 * ((cc + swp) & 3) + parq;
                const short8 vf = *(const short8*)(tv + sv * 16);
                oacc[ds] = __builtin_amdgcn_mfma_f32_32x32x16_bf16(pf, vf, oacc[ds], 0, 0, 0);
            }
        }
    }

    // ---- epilogue: bf16 partial O + fp32 partial l ----
    u16* ob = Opart + ((size_t)split * BN + q0) * DIM;
    #pragma unroll
    for (int ds = 0; ds < 8; ++ds) {
        #pragma unroll
        for (int r = 0; r < 16; ++r) {
            const int ql = (r & 3) + 8 * (r >> 2) + 4 * g1;
            ob[(size_t)ql * DIM + ds * 32 + c31] = f2bf(oacc[ds][r]);
        }
    }
    lp += __shfl_xor(lp, 32, 64);
    if (g1 == 0) lpart[(size_t)split * BN + q0 + c31] = lp;
}

// ---------------- kernel 3: merge splits, blend, final l2-normalize ----------------
__global__ __launch_bounds__(256) void k_combine(
        const float* __restrict__ feats, const u16* __restrict__ Opart,
        const float* __restrict__ lpart, float* __restrict__ out) {
    const int row = blockIdx.x * 4 + (threadIdx.x >> 6);
    const int lane = threadIdx.x & 63;

    float L = 0.f;
    #pragma unroll
    for (int s = 0; s < NSPLIT; ++s) L += lpart[(size_t)s * BN + row];

    float a0 = 0.f, a1 = 0.f, a2 = 0.f, a3 = 0.f;
    #pragma unroll
    for (int s = 0; s < NSPLIT; ++s) {
        const ushort4 o = *(const ushort4*)(Opart + ((size_t)s * BN + row) * DIM + lane * 4);
        a0 += bf2f(o.x); a1 += bf2f(o.y); a2 += bf2f(o.z); a3 += bf2f(o.w);
    }
    const float invL = 1.0f / L;

    const float4 v = *(const float4*)(feats + (size_t)row * DIM + lane * 4);
    float ss = v.x * v.x + v.y * v.y + v.z * v.z + v.w * v.w;
    #pragma unroll
    for (int off = 1; off < 64; off <<= 1) ss += __shfl_xor(ss, off, 64);
    const float invf = 1.0f / fmaxf(sqrtf(ss), 1e-12f);

    const float yx = 0.8f * v.x * invf + 0.2f * a0 * invL;
    const float yy = 0.8f * v.y * invf + 0.2f * a1 * invL;
    const float yz = 0.8f * v.z * invf + 0.2f * a2 * invL;
    const float yw = 0.8f * v.w * invf + 0.2f * a3 * invL;

    float s2 = yx * yx + yy * yy + yz * yz + yw * yw;
    #pragma unroll
    for (int off = 1; off < 64; off <<= 1) s2 += __shfl_xor(s2, off, 64);
    const float invn = 1.0f / fmaxf(sqrtf(s2), 1e-12f);

    float4 o; o.x = yx * invn; o.y = yy * invn; o.z = yz * invn; o.w = yw * invn;
    *(float4*)(out + (size_t)row * DIM + lane * 4) = o;
}

// ---------------- launcher ----------------
extern "C" void kernel_launch(void* const* d_in, const int* in_sizes, int n_in,
                              void* d_out, int out_size, void* d_ws, size_t ws_size,
                              hipStream_t stream) {
    const float* feats = (const float*)d_in[0];
    float* out = (float*)d_out;
    char* ws = (char*)d_ws;

    // ws: fb bf16 4MB | fv bf16 4MB | Opart bf16 32MB | lpart fp32 256KB
    u16* fb = (u16*)ws;
    u16* fv = (u16*)(ws + (size_t)BN * DIM * 2);
    u16* Op = (u16*)(ws + (size_t)BN * DIM * 4);
    float* lp = (float*)(ws + (size_t)BN * DIM * 4 + (size_t)NSPLIT * BN * DIM * 2);

    k_prep<<<BN / 32, 256, 0, stream>>>(feats, fb, fv);
    k_flash<<<(BN / 128) * NSPLIT, 256, 0, stream>>>(fb, fv, Op, lp);
    k_combine<<<BN / 4, 256, 0, stream>>>(feats, Op, lp, out);
}

// Round 5
// 146.025 us; speedup vs baseline: 1.3918x; 1.0267x over previous
//
#include <hip/hip_runtime.h>

typedef unsigned char u8;
typedef unsigned short u16;
typedef unsigned int u32;
typedef unsigned long long u64;
typedef long long i64;
typedef __attribute__((ext_vector_type(16))) float floatx16;

#define BN 8192
#define DIM 256
#define NSPLIT 8
#define KPS (BN / NSPLIT)   // 1024 keys per split
#define BKN 32              // keys per iter
#define NIT (KPS / BKN)     // 32 iters

__device__ __forceinline__ u16 f2bf(float x) {
    u32 u = __builtin_bit_cast(u32, x);
    u = (u + 0x7fffu + ((u >> 16) & 1u)) >> 16;
    return (u16)u;
}
__device__ __forceinline__ float bf2f(u16 h) {
    return __builtin_bit_cast(float, (u32)h << 16);
}
__device__ __forceinline__ u64 pack4bf(float a, float b, float c, float d) {
    return (u64)f2bf(a) | ((u64)f2bf(b) << 16) | ((u64)f2bf(c) << 32) | ((u64)f2bf(d) << 48);
}
__device__ __forceinline__ u32 pk_fp8(float a, float b, float c, float d) {
    int v = __builtin_amdgcn_cvt_pk_fp8_f32(a, b, 0, false);
    v = __builtin_amdgcn_cvt_pk_fp8_f32(c, d, v, true);
    return (u32)v;
}
__device__ __forceinline__ void gl_lds16(const void* g, void* l) {
    __builtin_amdgcn_global_load_lds(
        (const __attribute__((address_space(1))) u32*)g,
        (__attribute__((address_space(3))) u32*)l, 16, 0, 0);
}

// ---------------- kernel 1: row l2-norm -> fp8 fb (row-major) + fp8 fv (V^T tile images) ----
// 256 blocks x 256 thr; block kb handles keys kb*32..kb*32+31.
// fv[kb] is an 8 KB image of V^T (256 d-rows x 32 keys, fp8), 8B slots:
//   slot(d,c) = d*4 + ((c + (d>>2)) & 3) holds V[8c+j][d], j=0..7
__global__ __launch_bounds__(256) void k_prep(const float* __restrict__ in,
                                              u8* __restrict__ fb, u8* __restrict__ fv) {
    __shared__ u16 t[32 * 260];
    const int tid = threadIdx.x;
    const int wave = tid >> 6, lane = tid & 63;
    const int kb = blockIdx.x, r0 = kb * 32;
    #pragma unroll
    for (int i = 0; i < 8; ++i) {
        const int rl = wave * 8 + i;
        const float4 v = *(const float4*)(in + (size_t)(r0 + rl) * DIM + lane * 4);
        float ss = v.x * v.x + v.y * v.y + v.z * v.z + v.w * v.w;
        #pragma unroll
        for (int off = 1; off < 64; off <<= 1) ss += __shfl_xor(ss, off, 64);
        const float inv = 1.0f / fmaxf(sqrtf(ss), 1e-12f);
        const float n0 = v.x * inv, n1 = v.y * inv, n2 = v.z * inv, n3 = v.w * inv;
        *(u32*)(fb + (size_t)(r0 + rl) * DIM + lane * 4) = pk_fp8(n0, n1, n2, n3);
        *(u64*)(&t[rl * 260 + lane * 4]) = pack4bf(n0, n1, n2, n3);
    }
    __syncthreads();
    #pragma unroll
    for (int i = 0; i < 4; ++i) {
        const int S = i * 256 + tid;              // 8-byte slot index 0..1023
        const int d = S >> 2;
        const int c = ((S & 3) - (d >> 2)) & 3;   // key octet
        float f[8];
        #pragma unroll
        for (int j = 0; j < 8; ++j) f[j] = bf2f(t[(8 * c + j) * 260 + d]);
        const u32 lo = pk_fp8(f[0], f[1], f[2], f[3]);
        const u32 hi = pk_fp8(f[4], f[5], f[6], f[7]);
        *(u64*)(fv + (size_t)kb * 8192 + S * 8) = ((u64)hi << 32) | lo;
    }
}

// ---------------- kernel 2: fp8 flash attention, no-max softmax, split-K ----------------
// 256 blocks (1/CU), 4 waves, 64 q/wave (two 32-q subtiles), 32x32x16 fp8 MFMA.
// Double-buffered 8KB tiles, 1 barrier/iter, DMA(it+1) flies across compute(it).
// P stays in registers: S^T C/D cols=q == PV A rows=q; two 32-bit shfl_xor(32) build A-frags.
__global__ __launch_bounds__(256, 1) void k_flash(
        const u8* __restrict__ fb, const u8* __restrict__ fv,
        u16* __restrict__ Opart, float* __restrict__ lpart) {
    __shared__ u8 tileK[2][8192];   // key-major fp8, chunk-swizzled (16B chunks)
    __shared__ u8 tileV[2][8192];   // pre-swizzled V^T fp8 image

    const int tid = threadIdx.x;
    const int wave = tid >> 6, lane = tid & 63;
    const int c31 = lane & 31, g1 = lane >> 5;
    const int split = blockIdx.x & (NSPLIT - 1);
    const int qblk = blockIdx.x >> 3;
    const int q0 = qblk * 256 + wave * 64;
    const int key0 = split * KPS;

    // Q B-frags (fp8, loop-invariant): B[k=g1*8+j][n=c31] = Q[q][kc*16+g1*8+j]
    i64 qf0[16], qf1[16];
    #pragma unroll
    for (int kc = 0; kc < 16; ++kc) {
        qf0[kc] = *(const i64*)(fb + (size_t)(q0 + c31) * DIM + kc * 16 + g1 * 8);
        qf1[kc] = *(const i64*)(fb + (size_t)(q0 + 32 + c31) * DIM + kc * 16 + g1 * 8);
    }

    floatx16 o0[8], o1[8];
    #pragma unroll
    for (int i = 0; i < 8; ++i)
        #pragma unroll
        for (int r = 0; r < 16; ++r) { o0[i][r] = 0.f; o1[i][r] = 0.f; }
    float l0 = 0.f, l1 = 0.f;

    // K DMA source offsets (swizzle on global side; LDS dst lane-linear)
    int offK[2];
    #pragma unroll
    for (int i = 0; i < 2; ++i) {
        const int S = wave * 128 + i * 64 + lane;   // 16B slot
        const int r = S >> 4, s = S & 15;
        const int c = (s & 8) | ((s ^ r) & 7);
        offK[i] = r * 256 + c * 16;
    }
    const u8* gK = fb + (size_t)key0 * DIM;
    const u8* gV = fv + (size_t)(key0 >> 5) * 8192;

    auto stage = [&](int s, int b) {
        const size_t o = (size_t)s * 8192;
        u8* lK = &tileK[b][0] + wave * 2048;
        u8* lV = &tileV[b][0] + wave * 2048;
        #pragma unroll
        for (int i = 0; i < 2; ++i) gl_lds16(gK + o + offK[i], lK + i * 1024);
        #pragma unroll
        for (int i = 0; i < 2; ++i)
            gl_lds16(gV + o + wave * 2048 + i * 1024 + lane * 16, lV + i * 1024);
    };

    stage(0, 0);
    for (int it = 0; it < NIT; ++it) {
        const int b = it & 1;
        __syncthreads();                   // drains DMA(it), issued one iter ago
        if (it + 1 < NIT) stage(it + 1, b ^ 1);

        // ---- S^T = K * Q^T (contract d=256, 16 A-frag reads feed 32 MFMA) ----
        floatx16 s0, s1;
        #pragma unroll
        for (int r = 0; r < 16; ++r) { s0[r] = 0.f; s1[r] = 0.f; }
        const u8* tk = &tileK[b][0];
        #pragma unroll
        for (int kc = 0; kc < 16; ++kc) {
            const int sw = (kc & 8) | ((kc ^ c31) & 7);
            const i64 a = *(const i64*)(tk + c31 * 256 + sw * 16 + g1 * 8);
            s0 = __builtin_amdgcn_mfma_f32_32x32x16_fp8_fp8(a, qf0[kc], s0, 0, 0, 0);
            s1 = __builtin_amdgcn_mfma_f32_32x32x16_fp8_fp8(a, qf1[kc], s1, 0, 0, 0);
        }

        // ---- P = exp(S) -> fp8 A-frags in registers ----
        i64 A00, A01, A10, A11;
        {
            float e[16];
            #pragma unroll
            for (int r = 0; r < 16; ++r) { e[r] = __expf(s0[r]); l0 += e[r]; }
            u32 p[4];
            #pragma unroll
            for (int rr = 0; rr < 4; ++rr)
                p[rr] = pk_fp8(e[4 * rr], e[4 * rr + 1], e[4 * rr + 2], e[4 * rr + 3]);
            const u32 x0 = (u32)__shfl_xor((int)(g1 ? p[0] : p[1]), 32, 64);
            const u32 x1 = (u32)__shfl_xor((int)(g1 ? p[2] : p[3]), 32, 64);
            A00 = g1 ? (i64)(((u64)p[1] << 32) | x0) : (i64)(((u64)x0 << 32) | p[0]);
            A01 = g1 ? (i64)(((u64)p[3] << 32) | x1) : (i64)(((u64)x1 << 32) | p[2]);
        }
        {
            float e[16];
            #pragma unroll
            for (int r = 0; r < 16; ++r) { e[r] = __expf(s1[r]); l1 += e[r]; }
            u32 p[4];
            #pragma unroll
            for (int rr = 0; rr < 4; ++rr)
                p[rr] = pk_fp8(e[4 * rr], e[4 * rr + 1], e[4 * rr + 2], e[4 * rr + 3]);
            const u32 x0 = (u32)__shfl_xor((int)(g1 ? p[0] : p[1]), 32, 64);
            const u32 x1 = (u32)__shfl_xor((int)(g1 ? p[2] : p[3]), 32, 64);
            A10 = g1 ? (i64)(((u64)p[1] << 32) | x0) : (i64)(((u64)x0 << 32) | p[0]);
            A11 = g1 ? (i64)(((u64)p[3] << 32) | x1) : (i64)(((u64)x1 << 32) | p[2]);
        }

        // ---- O += P * V (16 B-frag reads feed 32 MFMA) ----
        const u8* tv = &tileV[b][0];
        #pragma unroll
        for (int kc2 = 0; kc2 < 2; ++kc2) {
            const int cc = kc2 * 2 + g1;
            const i64 pa0 = kc2 ? A01 : A00;
            const i64 pa1 = kc2 ? A11 : A10;
            const int csw = (cc + (c31 >> 2)) & 3;
            #pragma unroll
            for (int ds = 0; ds < 8; ++ds) {
                const int slot = (ds * 32 + c31) * 4 + csw;
                const i64 vf = *(const i64*)(tv + slot * 8);
                o0[ds] = __builtin_amdgcn_mfma_f32_32x32x16_fp8_fp8(pa0, vf, o0[ds], 0, 0, 0);
                o1[ds] = __builtin_amdgcn_mfma_f32_32x32x16_fp8_fp8(pa1, vf, o1[ds], 0, 0, 0);
            }
        }
    }

    // ---- epilogue: bf16 partial O + fp32 partial l ----
    u16* ob = Opart + ((size_t)split * BN + q0) * DIM;
    #pragma unroll
    for (int ds = 0; ds < 8; ++ds) {
        #pragma unroll
        for (int r = 0; r < 16; ++r) {
            const int ql = (r & 3) + 8 * (r >> 2) + 4 * g1;
            ob[(size_t)ql * DIM + ds * 32 + c31] = f2bf(o0[ds][r]);
            ob[(size_t)(32 + ql) * DIM + ds * 32 + c31] = f2bf(o1[ds][r]);
        }
    }
    l0 += __shfl_xor(l0, 32, 64);
    l1 += __shfl_xor(l1, 32, 64);
    if (g1 == 0) {
        lpart[(size_t)split * BN + q0 + c31] = l0;
        lpart[(size_t)split * BN + q0 + 32 + c31] = l1;
    }
}

// ---------------- kernel 3: merge splits, blend, final l2-normalize ----------------
__global__ __launch_bounds__(256) void k_combine(
        const float* __restrict__ feats, const u16* __restrict__ Opart,
        const float* __restrict__ lpart, float* __restrict__ out) {
    const int row = blockIdx.x * 4 + (threadIdx.x >> 6);
    const int lane = threadIdx.x & 63;

    float L = 0.f;
    #pragma unroll
    for (int s = 0; s < NSPLIT; ++s) L += lpart[(size_t)s * BN + row];

    float a0 = 0.f, a1 = 0.f, a2 = 0.f, a3 = 0.f;
    #pragma unroll
    for (int s = 0; s < NSPLIT; ++s) {
        const ushort4 o = *(const ushort4*)(Opart + ((size_t)s * BN + row) * DIM + lane * 4);
        a0 += bf2f(o.x); a1 += bf2f(o.y); a2 += bf2f(o.z); a3 += bf2f(o.w);
    }
    const float invL = 1.0f / L;

    const float4 v = *(const float4*)(feats + (size_t)row * DIM + lane * 4);
    float ss = v.x * v.x + v.y * v.y + v.z * v.z + v.w * v.w;
    #pragma unroll
    for (int off = 1; off < 64; off <<= 1) ss += __shfl_xor(ss, off, 64);
    const float invf = 1.0f / fmaxf(sqrtf(ss), 1e-12f);

    const float yx = 0.8f * v.x * invf + 0.2f * a0 * invL;
    const float yy = 0.8f * v.y * invf + 0.2f * a1 * invL;
    const float yz = 0.8f * v.z * invf + 0.2f * a2 * invL;
    const float yw = 0.8f * v.w * invf + 0.2f * a3 * invL;

    float s2 = yx * yx + yy * yy + yz * yz + yw * yw;
    #pragma unroll
    for (int off = 1; off < 64; off <<= 1) s2 += __shfl_xor(s2, off, 64);
    const float invn = 1.0f / fmaxf(sqrtf(s2), 1e-12f);

    float4 o; o.x = yx * invn; o.y = yy * invn; o.z = yz * invn; o.w = yw * invn;
    *(float4*)(out + (size_t)row * DIM + lane * 4) = o;
}

// ---------------- launcher ----------------
extern "C" void kernel_launch(void* const* d_in, const int* in_sizes, int n_in,
                              void* d_out, int out_size, void* d_ws, size_t ws_size,
                              hipStream_t stream) {
    const float* feats = (const float*)d_in[0];
    float* out = (float*)d_out;
    char* ws = (char*)d_ws;

    // ws: fb fp8 2MB | fv fp8 2MB | Opart bf16 32MB | lpart fp32 256KB
    u8* fb = (u8*)ws;
    u8* fv = (u8*)(ws + (size_t)BN * DIM);
    u16* Op = (u16*)(ws + (size_t)BN * DIM * 2);
    float* lp = (float*)(ws + (size_t)BN * DIM * 2 + (size_t)NSPLIT * BN * DIM * 2);

    k_prep<<<BN / 32, 256, 0, stream>>>(feats, fb, fv);
    k_flash<<<(BN / 256) * NSPLIT, 256, 0, stream>>>(fb, fv, Op, lp);
    k_combine<<<BN / 4, 256, 0, stream>>>(feats, Op, lp, out);
}